// Round 8
// baseline (470.657 us; speedup 1.0000x reference)
//
#include <hip/hip_runtime.h>
#include <hip/hip_fp16.h>

// ---------------------------------------------------------------------------
// QGNN traffic predictor. R8: GRU weights in registers (no W LDS, 4 blk/CU);
// GEMM A-tiles in registers (B-only LDS double-buffer).
// ---------------------------------------------------------------------------

#define NND 307
#define BBATCH 128
#define LSEQ 12
#define HIDN 64
#define JTOT (BBATCH*LSEQ*HIDN)   // 98304
#define NROWS (NND*BBATCH)        // 39296
#define KPAD 320
#define MSTR 312                  // S0T/S1T row stride (halves)
#define F2S 80                    // feat2 row stride (halves)

// workspace layout (float units)
#define OFF_DINV  0
#define OFF_HAM0  320
#define OFF_HAM1B 576             // __half ham1B [8][64][8] = 2048 fl
#define OFF_WIHP  4672            // __half [10][192][8]
#define OFF_WHHP  12352           // __half [8][192][8]
#define OFF_ANG   18496           // __half anG [10][4][320][8] = 51200 fl
#define OFF_S1T   69696           // __half S1T [98304][312] = 15335424 fl
#define OFF_S0T   15405120        // __half S0T [98304][312]  (aliases feat2)
#define OFF_FEATH 15405120        // __half feat2 [12][39296][80] = 18862080 fl

typedef _Float16 half8 __attribute__((ext_vector_type(8)));
typedef float f32x4 __attribute__((ext_vector_type(4)));

__device__ __forceinline__ float tanh_fast(float v){
  float e2 = exp2f(2.88539008f * v);     // exp(2v)
  return 1.f - 2.f/(e2 + 1.f);
}

// ---------------- adjacency normalization ----------------
__global__ void k_dinv(const float* __restrict__ adj, float* __restrict__ dinv){
  int n = blockIdx.x; int lane = threadIdx.x;
  float s = 0.f;
  for (int m = lane; m < NND; m += 64) s += adj[n*NND+m] + (m==n ? 1.f : 0.f);
  #pragma unroll
  for (int o = 32; o > 0; o >>= 1) s += __shfl_down(s, o);
  if (lane == 0) dinv[n] = 1.f/sqrtf(s);
}

// a_n fp16, granule-tiled: anG[((ks*4+g)*320 + row)*8 + j] = a_n[row][ks*32+g*8+j]
__global__ void k_anG(const float* __restrict__ adj, const float* __restrict__ dinv,
                      __half* __restrict__ anG){
  int id = blockIdx.x*256 + threadIdx.x;
  if (id >= KPAD*KPAD) return;
  int n = id / KPAD, m = id % KPAD;
  float v = 0.f;
  if (n < NND && m < NND)
    v = dinv[n] * (adj[n*NND+m] + (n==m ? 1.f : 0.f)) * dinv[m];
  int ks = m >> 5, g = (m >> 3) & 3, j = m & 7;
  anG[(((ks*4 + g)*320 + n) << 3) + j] = __float2half(v);
}

// ---------------- Hamilton matrices (ham0T f32; ham1 -> fp16 B-granule) -----
__global__ void k_ham(const float* __restrict__ w0, const float* __restrict__ w1,
                      float* __restrict__ ham0T, __half* __restrict__ ham1B){
  const int  comp[4][4] = {{0,1,2,3},{1,0,3,2},{2,3,0,1},{3,2,1,0}};
  const float sgn[4][4] = {{1.f,1.f,1.f,1.f},{-1.f,1.f,1.f,-1.f},
                           {-1.f,-1.f,1.f,1.f},{-1.f,1.f,-1.f,1.f}};
  int id = blockIdx.x*256 + threadIdx.x;
  if (id < 64) {
    int d = id, qb = d>>4, cc = d&15;
    #pragma unroll
    for (int c = 0; c < 4; ++c)
      ham0T[d*4+c] = sgn[c][qb] * w0[comp[c][qb]*16 + cc];
  }
  int id1 = id - 256;
  if (id1 >= 0 && id1 < 4096) {
    int din = id1 >> 6, d = id1 & 63;      // ham1[din][dout=d]
    int pb = din>>4, rr = din&15, qb = d>>4, cc = d&15;
    float val = sgn[pb][qb] * w1[rr*64 + comp[pb][qb]*16 + cc];
    ham1B[(((din>>3)*64) + d)*8 + (din&7)] = __float2half(val);
  }
}

// ---------------- GRU weight packing: [granule][col][8] fp16 ----------------
__global__ void k_wT(const float* __restrict__ w_ih, const float* __restrict__ w_hh,
                     __half* __restrict__ wihP, __half* __restrict__ whhP){
  int id = blockIdx.x*256 + threadIdx.x;
  if (id < 10*192*8) {
    int j = id & 7, col = (id >> 3) % 192, g = id / (192*8);
    int k = g*8 + j;
    wihP[id] = __float2half(k < 75 ? w_ih[col*75 + k] : 0.f);
  } else {
    int id2 = id - 10*192*8;
    if (id2 < 8*192*8) {
      int j = id2 & 7, col = (id2 >> 3) % 192, g = id2 / (192*8);
      whhP[id2] = __float2half(w_hh[col*64 + g*8 + j]);
    }
  }
}

// ---------------- S0T = (hist x ham0)^T : [j=(b,l,d)][k] fp16 ---------------
__global__ __launch_bounds__(256) void k_s0(const float* __restrict__ hist,
                                            const float* __restrict__ ham0Tg,
                                            __half* __restrict__ S0T){
  __shared__ float4 histL[320];
  const int t = threadIdx.x;
  const int bl = blockIdx.x;             // b*12 + l
  for (int k = t; k < 320; k += 256)
    histL[k] = (k < NND) ? *(const float4*)(hist + ((size_t)bl*NND + k)*4)
                         : make_float4(0.f,0.f,0.f,0.f);
  __syncthreads();
  if (t < 154) {
    const int k0 = 2*t;
    const float4 hA = histL[k0], hB = histL[k0+1];
    const size_t jb = (size_t)bl*64;
    for (int d = 0; d < 64; ++d) {
      float4 h0 = *(const float4*)(ham0Tg + d*4);   // uniform -> s_load
      float vA = hA.x*h0.x + hA.y*h0.y + hA.z*h0.z + hA.w*h0.w;
      float vB = hB.x*h0.x + hB.y*h0.y + hB.z*h0.z + hB.w*h0.w;
      __half2 p = __floats2half2_rn(vA, vB);
      if (k0 + 1 < NND) *(__half2*)(S0T + (jb + d)*MSTR + k0) = p;
      else              S0T[(jb + d)*MSTR + k0] = __low2half(p);
    }
  }
}

// ---------------- feat extras: speed + embeddings into feat2 cols 64..79 ----
__global__ void k_extras(const float* __restrict__ hist, const float* __restrict__ tid_emb,
                         const float* __restrict__ dw_emb, __half* __restrict__ feat2){
  int id = blockIdx.x*256 + threadIdx.x;   // over LSEQ*NROWS
  if (id >= LSEQ*NROWS) return;
  int lq = id / NROWS, row = id % NROWS;
  int n = row >> 7, b = row & 127;
  const float* h = hist + ((size_t)(b*LSEQ + lq)*NND + n)*4;
  union { __half h16[16]; uint4 v[2]; } u;
  u.h16[0] = __float2half(h[0]);
  int ti  = (int)rintf(h[1]*287.f);
  int dwi = (int)rintf(h[2]*6.f);
  #pragma unroll
  for (int c = 0; c < 5; ++c) u.h16[1+c] = __float2half(tid_emb[ti*5+c]);
  #pragma unroll
  for (int c = 0; c < 5; ++c) u.h16[6+c] = __float2half(dw_emb[dwi*5+c]);
  #pragma unroll
  for (int c = 11; c < 16; ++c) u.h16[c] = __float2half(0.f);
  uint4* dst = (uint4*)(feat2 + (size_t)id*F2S + 64);
  dst[0] = u.v[0]; dst[1] = u.v[1];
}

// ---------------- GEMM1 (MFMA): X1 = a_n @ S0; epi: BN0+tanh, @ham1 (MFMA) --
struct SG1 {
  union {
    struct { __half B[2][4][128][8]; } m;                                      // 16384B
    struct { __half xh[2][8][64][8]; __half h1b[8][64][8]; __half s1l[128][72]; } e; // 43008B
  } u;
  float sc[64], bi[64];
};

__global__ __launch_bounds__(256) void k_gemm1(
    const __half* __restrict__ anG, const __half* __restrict__ S0T,
    const __half* __restrict__ ham1Bg,
    const float* __restrict__ bng, const float* __restrict__ bnb,
    const float* __restrict__ bnm, const float* __restrict__ bnv,
    __half* __restrict__ S1T){
  __shared__ SG1 s;
  const int t = threadIdx.x;
  const int l = t & 63, wv = t >> 6;
  // XCD-aware j-major mapping
  const int xcd = blockIdx.x & 7, idx = blockIdx.x >> 3;
  const int bidj = xcd*96 + idx/5, bidm = idx % 5;
  const int m0 = bidm*64, j0 = bidj*128;
  if (t < 64) {
    float sc = bng[t] / sqrtf(bnv[t] + 1e-5f);
    s.sc[t] = sc; s.bi[t] = bnb[t] - bnm[t]*sc;
  }

  const int jB = t >> 1, hB = t & 1;
  const int moff = (wv>>1)*32, joff = (wv&1)*64;

  // A fragments -> registers (coalesced 256B per 16-lane group)
  half8 areg[10][2];
  #pragma unroll
  for (int ks = 0; ks < 10; ++ks)
    #pragma unroll
    for (int mf = 0; mf < 2; ++mf)
      areg[ks][mf] = *(const half8*)(anG +
        (((ks*4 + (l>>4))*320) + m0 + moff + mf*16 + (l&15))*8);

  f32x4 acc[2][4];
  #pragma unroll
  for (int a=0;a<2;++a)
    #pragma unroll
    for (int b=0;b<4;++b) acc[a][b] = (f32x4){0.f,0.f,0.f,0.f};

  {  // prologue: stage B ks=0
    const __half* bs = S0T + (size_t)(j0 + jB)*MSTR + hB*16;
    *(uint4*)&s.u.m.B[0][hB*2][jB][0]   = *(const uint4*)bs;
    *(uint4*)&s.u.m.B[0][hB*2+1][jB][0] = *(const uint4*)(bs + 8);
  }
  __syncthreads();

  int cur = 0;
  #pragma unroll
  for (int ks = 0; ks < 10; ++ks) {
    uint4 nb0, nb1;
    if (ks < 9) {
      const __half* bs = S0T + (size_t)(j0 + jB)*MSTR + (ks+1)*32 + hB*16;
      nb0 = *(const uint4*)bs;
      nb1 = *(const uint4*)(bs + 8);
    }
    half8 b8[4];
    #pragma unroll
    for (int jf = 0; jf < 4; ++jf)
      b8[jf] = *(const half8*)&s.u.m.B[cur][l>>4][joff + jf*16 + (l&15)][0];
    #pragma unroll
    for (int mf = 0; mf < 2; ++mf)
      #pragma unroll
      for (int jf = 0; jf < 4; ++jf)
        acc[mf][jf] = __builtin_amdgcn_mfma_f32_16x16x32_f16(areg[ks][mf], b8[jf], acc[mf][jf], 0, 0, 0);
    if (ks < 9) {
      *(uint4*)&s.u.m.B[cur^1][hB*2][jB][0]   = nb0;
      *(uint4*)&s.u.m.B[cur^1][hB*2+1][jB][0] = nb1;
      __syncthreads();
      cur ^= 1;
    }
  }
  __syncthreads();                       // main tiles dead; union reuse safe

  // stage ham1B (8KB) + BN0/tanh -> xh (fp16, A-granule layout)
  {
    const uint4* srcg = (const uint4*)ham1Bg;
    uint4* dstg = (uint4*)&s.u.e.h1b[0][0][0];
    #pragma unroll
    for (int i = 0; i < 2; ++i) dstg[t + i*256] = srcg[t + i*256];
  }
  #pragma unroll
  for (int mf = 0; mf < 2; ++mf)
    #pragma unroll
    for (int jf = 0; jf < 4; ++jf)
      #pragma unroll
      for (int r = 0; r < 4; ++r) {
        int mm = moff + mf*16 + (l>>4)*4 + r;
        int jc = joff + jf*16 + (l&15);
        int d = jc & 63;
        float v = tanh_fast(acc[mf][jf][r]*s.sc[d] + s.bi[d]);
        s.u.e.xh[jc>>6][d>>3][mm][d&7] = __float2half(v);
      }
  __syncthreads();
  // second GEMM on MFMA: C2[node][dout] = xh(bl) @ ham1, bl = wv&1
  f32x4 acc2[2][4];
  #pragma unroll
  for (int a=0;a<2;++a)
    #pragma unroll
    for (int b=0;b<4;++b) acc2[a][b] = (f32x4){0.f,0.f,0.f,0.f};
  const int gq = l >> 4, cb = l & 15;
  const int blw = wv & 1;
  #pragma unroll
  for (int ks2 = 0; ks2 < 2; ++ks2) {
    half8 a2[2];
    #pragma unroll
    for (int mf = 0; mf < 2; ++mf)
      a2[mf] = *(const half8*)&s.u.e.xh[blw][ks2*4+gq][moff + mf*16 + cb][0];
    #pragma unroll
    for (int jf = 0; jf < 4; ++jf) {
      half8 b2 = *(const half8*)&s.u.e.h1b[ks2*4+gq][jf*16 + cb][0];
      #pragma unroll
      for (int mf = 0; mf < 2; ++mf)
        acc2[mf][jf] = __builtin_amdgcn_mfma_f32_16x16x32_f16(a2[mf], b2, acc2[mf][jf], 0, 0, 0);
    }
  }
  // C2 -> s1l[jout 128][node 72]
  #pragma unroll
  for (int mf = 0; mf < 2; ++mf)
    #pragma unroll
    for (int jf = 0; jf < 4; ++jf)
      #pragma unroll
      for (int r = 0; r < 4; ++r) {
        int node = moff + mf*16 + gq*4 + r;
        int ro = blw*64 + jf*16 + cb;
        s.u.e.s1l[ro][node] = __float2half(acc2[mf][jf][r]);
      }
  __syncthreads();
  // copy out: row jj -> S1T[j0+jj][m0..m0+63]
  {
    int jj = t >> 1, hf = t & 1;
    __half* dst = S1T + (size_t)(j0 + jj)*MSTR + m0 + hf*32;
    const __half* srcl = &s.u.e.s1l[jj][hf*32];
    #pragma unroll
    for (int i = 0; i < 4; ++i)
      if (m0 + hf*32 + i*8 < MSTR)
        *(uint4*)(dst + i*8) = *(const uint4*)(srcl + i*8);
  }
}

// ---------------- GEMM2 (MFMA): X2 = a_n @ S1; epi: BN1+tanh -> feat2 -------
struct SG2 {
  union {
    struct { __half B[2][4][128][8]; } m;  // 16384B
    struct { __half x2[64][2][72]; } e;    // 18432B
  } u;
  float sc[64], bi[64];
};

__global__ __launch_bounds__(256) void k_gemm2(
    const __half* __restrict__ anG, const __half* __restrict__ S1T,
    const float* __restrict__ bng, const float* __restrict__ bnb,
    const float* __restrict__ bnm, const float* __restrict__ bnv,
    __half* __restrict__ feat2){
  __shared__ SG2 s;
  const int t = threadIdx.x;
  const int l = t & 63, wv = t >> 6;
  const int xcd = blockIdx.x & 7, idx = blockIdx.x >> 3;
  const int bidj = xcd*96 + idx/5, bidm = idx % 5;
  const int m0 = bidm*64, j0 = bidj*128;
  if (t < 64) {
    float sc = bng[64+t] / sqrtf(bnv[64+t] + 1e-5f);
    s.sc[t] = sc; s.bi[t] = bnb[64+t] - bnm[64+t]*sc;
  }
  const int jB = t >> 1, hB = t & 1;
  const int moff = (wv>>1)*32, joff = (wv&1)*64;

  half8 areg[10][2];
  #pragma unroll
  for (int ks = 0; ks < 10; ++ks)
    #pragma unroll
    for (int mf = 0; mf < 2; ++mf)
      areg[ks][mf] = *(const half8*)(anG +
        (((ks*4 + (l>>4))*320) + m0 + moff + mf*16 + (l&15))*8);

  f32x4 acc[2][4];
  #pragma unroll
  for (int a=0;a<2;++a)
    #pragma unroll
    for (int b=0;b<4;++b) acc[a][b] = (f32x4){0.f,0.f,0.f,0.f};

  {
    const __half* bs = S1T + (size_t)(j0 + jB)*MSTR + hB*16;
    *(uint4*)&s.u.m.B[0][hB*2][jB][0]   = *(const uint4*)bs;
    *(uint4*)&s.u.m.B[0][hB*2+1][jB][0] = *(const uint4*)(bs + 8);
  }
  __syncthreads();

  int cur = 0;
  #pragma unroll
  for (int ks = 0; ks < 10; ++ks) {
    uint4 nb0, nb1;
    if (ks < 9) {
      const __half* bs = S1T + (size_t)(j0 + jB)*MSTR + (ks+1)*32 + hB*16;
      nb0 = *(const uint4*)bs;
      nb1 = *(const uint4*)(bs + 8);
    }
    half8 b8[4];
    #pragma unroll
    for (int jf = 0; jf < 4; ++jf)
      b8[jf] = *(const half8*)&s.u.m.B[cur][l>>4][joff + jf*16 + (l&15)][0];
    #pragma unroll
    for (int mf = 0; mf < 2; ++mf)
      #pragma unroll
      for (int jf = 0; jf < 4; ++jf)
        acc[mf][jf] = __builtin_amdgcn_mfma_f32_16x16x32_f16(areg[ks][mf], b8[jf], acc[mf][jf], 0, 0, 0);
    if (ks < 9) {
      *(uint4*)&s.u.m.B[cur^1][hB*2][jB][0]   = nb0;
      *(uint4*)&s.u.m.B[cur^1][hB*2+1][jB][0] = nb1;
      __syncthreads();
      cur ^= 1;
    }
  }
  __syncthreads();
  // BN1 + tanh -> x2[m][bl][d]
  #pragma unroll
  for (int mf = 0; mf < 2; ++mf)
    #pragma unroll
    for (int jf = 0; jf < 4; ++jf)
      #pragma unroll
      for (int r = 0; r < 4; ++r) {
        int mm = moff + mf*16 + (l>>4)*4 + r;
        int jc = joff + jf*16 + (l&15);
        int bl = jc >> 6, d = jc & 63;
        float v = tanh_fast(acc[mf][jf][r]*s.sc[d] + s.bi[d]);
        s.u.e.x2[mm][bl][d] = __float2half(v);
      }
  __syncthreads();
  {
    int pr = t >> 1, hf = t & 1;
    int mm = pr >> 1, bl = pr & 1;
    int n = m0 + mm;
    if (n < NND) {
      int jg = j0 + bl*64;
      int b = jg/768, lq = (jg/64)%12;
      __half* dst = feat2 + ((size_t)lq*NROWS + n*BBATCH + b)*F2S + hf*32;
      const __half* srcl = &s.u.e.x2[mm][bl][hf*32];
      #pragma unroll
      for (int i = 0; i < 4; ++i)
        *(uint4*)(dst + i*8) = *(const uint4*)(srcl + i*8);
    }
  }
}

// ---------------- GRU (MFMA, 12 steps, weights in registers) ----------------
__global__ __launch_bounds__(512, 4) void k_gru(
    const __half* __restrict__ feat2, const __half* __restrict__ wihP,
    const __half* __restrict__ whhP, const float* __restrict__ b_ih,
    const float* __restrict__ b_hh, const float* __restrict__ fc_w,
    const float* __restrict__ fc_b, float* __restrict__ out){
  __shared__ __half xt[10*64*8];     // 10240 B
  __shared__ __half Hs[8*64*8];      // 8192 B
  __shared__ float red[4][2][16];

  const int t = threadIdx.x;
  const int l = t & 63, wv = t >> 6;
  const int mt = wv >> 1, ng = wv & 1;
  const int row0 = blockIdx.x * 64;
  const int gq = l >> 4, colb = l & 15;

  half8 hz;
  #pragma unroll
  for (int i = 0; i < 8; ++i) hz[i] = (_Float16)0.f;

  // weight fragments -> registers (identical values to old LDS reads)
  half8 wi[2][3][3];   // [s2][gate r/z/n][k-chunk]
  half8 wh[2][3][2];
  #pragma unroll
  for (int s2 = 0; s2 < 2; ++s2) {
    const int nt[3] = { ng*2 + s2, 4 + ng*2 + s2, 8 + ng*2 + s2 };
    #pragma unroll
    for (int g = 0; g < 3; ++g) {
      wi[s2][g][0] = *(const half8*)(wihP + (((0+gq)*192 + nt[g]*16 + colb) << 3));
      wi[s2][g][1] = *(const half8*)(wihP + (((4+gq)*192 + nt[g]*16 + colb) << 3));
      wi[s2][g][2] = (gq < 2) ? *(const half8*)(wihP + (((8+gq)*192 + nt[g]*16 + colb) << 3)) : hz;
      wh[s2][g][0] = *(const half8*)(whhP + (((0+gq)*192 + nt[g]*16 + colb) << 3));
      wh[s2][g][1] = *(const half8*)(whhP + (((4+gq)*192 + nt[g]*16 + colb) << 3));
    }
  }

  for (int i = t; i < 8*64; i += 512) ((uint4*)Hs)[i] = make_uint4(0,0,0,0);

  float bR[2], bZ[2], bI[2], bH[2], fw[2];
  #pragma unroll
  for (int s2 = 0; s2 < 2; ++s2) {
    int d = ng*32 + s2*16 + colb;
    bR[s2] = b_ih[d]     + b_hh[d];
    bZ[s2] = b_ih[64+d]  + b_hh[64+d];
    bI[s2] = b_ih[128+d];
    bH[s2] = b_hh[128+d];
    fw[s2] = fc_w[d];
  }
  const float fcb = fc_b[0];
  float hreg[8];
  #pragma unroll
  for (int i = 0; i < 8; ++i) hreg[i] = 0.f;

  const int rst = t >> 3, qst = t & 7;
  {
    const __half* src = feat2 + ((size_t)(row0 + rst))*F2S;
    *(uint4*)&xt[(qst*64 + rst)*8] = *(const uint4*)(src + qst*8);
    if (qst < 2) *(uint4*)&xt[((qst+8)*64 + rst)*8] = *(const uint4*)(src + (qst+8)*8);
  }
  __syncthreads();

  const int rowA = mt*16 + colb;

  for (int ts = 0; ts < 12; ++ts) {
    half8 agi0 = *(const half8*)&xt[((0+gq)*64 + rowA)*8];
    half8 agi1 = *(const half8*)&xt[((4+gq)*64 + rowA)*8];
    half8 agi2 = (gq < 2) ? *(const half8*)&xt[((8+gq)*64 + rowA)*8] : hz;
    half8 agh0 = *(const half8*)&Hs[((0+gq)*64 + rowA)*8];
    half8 agh1 = *(const half8*)&Hs[((4+gq)*64 + rowA)*8];
    f32x4 aR[2], aZ[2], aIn[2], aHn[2];
    #pragma unroll
    for (int s2 = 0; s2 < 2; ++s2) {
      aR[s2] = (f32x4){0.f,0.f,0.f,0.f}; aZ[s2] = (f32x4){0.f,0.f,0.f,0.f};
      aIn[s2] = (f32x4){0.f,0.f,0.f,0.f}; aHn[s2] = (f32x4){0.f,0.f,0.f,0.f};
    }
    #pragma unroll
    for (int s2 = 0; s2 < 2; ++s2) {
      aR[s2]  = __builtin_amdgcn_mfma_f32_16x16x32_f16(agi0, wi[s2][0][0], aR[s2], 0,0,0);
      aR[s2]  = __builtin_amdgcn_mfma_f32_16x16x32_f16(agi1, wi[s2][0][1], aR[s2], 0,0,0);
      aR[s2]  = __builtin_amdgcn_mfma_f32_16x16x32_f16(agi2, wi[s2][0][2], aR[s2], 0,0,0);
      aR[s2]  = __builtin_amdgcn_mfma_f32_16x16x32_f16(agh0, wh[s2][0][0], aR[s2], 0,0,0);
      aR[s2]  = __builtin_amdgcn_mfma_f32_16x16x32_f16(agh1, wh[s2][0][1], aR[s2], 0,0,0);
      aZ[s2]  = __builtin_amdgcn_mfma_f32_16x16x32_f16(agi0, wi[s2][1][0], aZ[s2], 0,0,0);
      aZ[s2]  = __builtin_amdgcn_mfma_f32_16x16x32_f16(agi1, wi[s2][1][1], aZ[s2], 0,0,0);
      aZ[s2]  = __builtin_amdgcn_mfma_f32_16x16x32_f16(agi2, wi[s2][1][2], aZ[s2], 0,0,0);
      aZ[s2]  = __builtin_amdgcn_mfma_f32_16x16x32_f16(agh0, wh[s2][1][0], aZ[s2], 0,0,0);
      aZ[s2]  = __builtin_amdgcn_mfma_f32_16x16x32_f16(agh1, wh[s2][1][1], aZ[s2], 0,0,0);
      aIn[s2] = __builtin_amdgcn_mfma_f32_16x16x32_f16(agi0, wi[s2][2][0], aIn[s2], 0,0,0);
      aIn[s2] = __builtin_amdgcn_mfma_f32_16x16x32_f16(agi1, wi[s2][2][1], aIn[s2], 0,0,0);
      aIn[s2] = __builtin_amdgcn_mfma_f32_16x16x32_f16(agi2, wi[s2][2][2], aIn[s2], 0,0,0);
      aHn[s2] = __builtin_amdgcn_mfma_f32_16x16x32_f16(agh0, wh[s2][2][0], aHn[s2], 0,0,0);
      aHn[s2] = __builtin_amdgcn_mfma_f32_16x16x32_f16(agh1, wh[s2][2][1], aHn[s2], 0,0,0);
    }
    float hnew[8];
    #pragma unroll
    for (int s2 = 0; s2 < 2; ++s2)
      #pragma unroll
      for (int rg = 0; rg < 4; ++rg) {
        const int i = s2*4 + rg;
        float pr = aR[s2][rg] + bR[s2];
        float pz = aZ[s2][rg] + bZ[s2];
        float pn = aIn[s2][rg] + bI[s2];
        float ph = aHn[s2][rg] + bH[s2];
        float r = 1.f / (1.f + exp2f(-1.44269504f * pr));
        float z = 1.f / (1.f + exp2f(-1.44269504f * pz));
        float e2 = exp2f(2.88539008f * (pn + r*ph));
        float nc = 1.f - 2.f/(e2 + 1.f);
        hnew[i] = (1.f - z)*nc + z*hreg[i];
        hreg[i] = hnew[i];
      }
    if (ts >= 9) {
      #pragma unroll
      for (int rg = 0; rg < 4; ++rg) {
        float p = fmaxf(hnew[rg],0.f)*fw[0] + fmaxf(hnew[4+rg],0.f)*fw[1];
        p += __shfl_xor(p, 1); p += __shfl_xor(p, 2);
        p += __shfl_xor(p, 4); p += __shfl_xor(p, 8);
        if (colb == 0) red[mt][ng][gq*4 + rg] = p;
      }
    }
    __syncthreads();
    if (ts >= 9 && ng == 0 && colb == 0) {
      #pragma unroll
      for (int rg = 0; rg < 4; ++rg) {
        int rr = gq*4 + rg;
        float sum = red[mt][0][rr] + red[mt][1][rr] + fcb;
        int grow = row0 + mt*16 + rr;
        out[((grow & 127)*3 + (ts-9))*NND + (grow >> 7)] = sum;
      }
    }
    if (ts < 11) {
      #pragma unroll
      for (int s2 = 0; s2 < 2; ++s2) {
        const int d = ng*32 + s2*16 + colb;
        #pragma unroll
        for (int rg = 0; rg < 4; ++rg) {
          int rw = mt*16 + gq*4 + rg;
          Hs[((d>>3)*64 + rw)*8 + (d&7)] = __float2half(hnew[s2*4+rg]);
        }
      }
      const __half* src = feat2 + ((size_t)(ts+1)*NROWS + row0 + rst)*F2S;
      *(uint4*)&xt[(qst*64 + rst)*8] = *(const uint4*)(src + qst*8);
      if (qst < 2) *(uint4*)&xt[((qst+8)*64 + rst)*8] = *(const uint4*)(src + (qst+8)*8);
    }
    __syncthreads();
  }
}

// ---------------------------------------------------------------------------
extern "C" void kernel_launch(void* const* d_in, const int* in_sizes, int n_in,
                              void* d_out, int out_size, void* d_ws, size_t ws_size,
                              hipStream_t stream) {
  const float* hist    = (const float*)d_in[0];
  const float* adj     = (const float*)d_in[1];
  const float* w0      = (const float*)d_in[2];
  const float* w1      = (const float*)d_in[3];
  const float* bng     = (const float*)d_in[4];
  const float* bnb     = (const float*)d_in[5];
  const float* bnm     = (const float*)d_in[6];
  const float* bnv     = (const float*)d_in[7];
  const float* tid_emb = (const float*)d_in[8];
  const float* dw_emb  = (const float*)d_in[9];
  const float* w_ih    = (const float*)d_in[10];
  const float* w_hh    = (const float*)d_in[11];
  const float* b_ih    = (const float*)d_in[12];
  const float* b_hh    = (const float*)d_in[13];
  const float* fc_w    = (const float*)d_in[14];
  const float* fc_b    = (const float*)d_in[15];

  float* wsf   = (float*)d_ws;
  float* dinv  = wsf + OFF_DINV;
  float* ham0T = wsf + OFF_HAM0;
  __half* ham1B = (__half*)(wsf + OFF_HAM1B);
  __half* wihP  = (__half*)(wsf + OFF_WIHP);
  __half* whhP  = (__half*)(wsf + OFF_WHHP);
  __half* anG   = (__half*)(wsf + OFF_ANG);
  __half* S1T   = (__half*)(wsf + OFF_S1T);
  __half* S0T   = (__half*)(wsf + OFF_S0T);
  __half* feat2 = (__half*)(wsf + OFF_FEATH);
  float* outp  = (float*)d_out;

  k_dinv  <<<NND, 64, 0, stream>>>(adj, dinv);
  k_anG   <<<(KPAD*KPAD + 255)/256, 256, 0, stream>>>(adj, dinv, anG);
  k_ham   <<<17, 256, 0, stream>>>(w0, w1, ham0T, ham1B);
  k_wT    <<<108, 256, 0, stream>>>(w_ih, w_hh, wihP, whhP);
  k_s0    <<<BBATCH*LSEQ, 256, 0, stream>>>(hist, ham0T, S0T);
  k_gemm1 <<<5*768, 256, 0, stream>>>(anG, S0T, ham1B, bng, bnb, bnm, bnv, S1T);
  // k_extras AFTER gemm1: feat2 aliases S0T
  k_extras<<<(LSEQ*NROWS + 255)/256, 256, 0, stream>>>(hist, tid_emb, dw_emb, feat2);
  k_gemm2 <<<5*768, 256, 0, stream>>>(anG, S1T, bng, bnb, bnm, bnv, feat2);
  k_gru   <<<NROWS/64, 512, 0, stream>>>(feat2, wihP, whhP, b_ih, b_hh, fc_w, fc_b, outp);
}